// Round 2
// baseline (738.877 us; speedup 1.0000x reference)
//
#include <hip/hip_runtime.h>
#include <hip/hip_bf16.h>
#include <stdint.h>

// ---- problem constants ----
#define N_IMG 32
#define C_IN  256
#define HW    56
#define PIX   3136            // 56*56
#define M_TOT 100352          // 32*3136
#define C_OUT 256
#define K_TOT 2304            // 256*9
#define HP    58
#define WPAD  58
#define OUT_IMG_STRIDE 802816 // 256*3136

// ---- GEMM tile config: BM=224 (4 image rows), BN=128, slab-reuse over 9 taps ----
#define BM 224
#define BN 128
#define SLAB_PIX 348                 // 6 padded rows * 58 cols
#define SLAB_SLOTS (SLAB_PIX * 4)    // 1392 16B slots per buffer (32 chans/pixel)

typedef __attribute__((ext_vector_type(8))) short bf16x8_t;   // 8 bf16 = 4 VGPRs
typedef __attribute__((ext_vector_type(4))) float f32x4_t;

// ---------------- pass 0: zero only the padded border (3.7 MB, not 55 MB) -----------
__global__ void border_zero_kernel(__hip_bfloat16* __restrict__ xpad) {
    int t = blockIdx.x * 256 + threadIdx.x;   // 32 n * 228 border px * 32 uint4 = 233472
    if (t >= 32 * 228 * 32) return;
    int n = t / (228 * 32);
    int r = t - n * (228 * 32);
    int px = r >> 5, part = r & 31;
    int hp, wp;
    if (px < 58)       { hp = 0;  wp = px; }
    else if (px < 116) { hp = 57; wp = px - 116 + 58; }
    else { int k = px - 116; hp = 1 + (k >> 1); wp = (k & 1) ? 57 : 0; }
    long e = (((long)n * HP + hp) * WPAD + wp) * C_IN + part * 8;
    *(uint4*)(xpad + e) = make_uint4(0u, 0u, 0u, 0u);
}

// ---------------- pass 1: NCHW fp32 -> padded NHWC bf16 transpose --------------------
__global__ void xform_kernel(const float* __restrict__ x, __hip_bfloat16* __restrict__ xpad) {
    __shared__ float tile[64][65];
    int b   = blockIdx.x;
    int n   = b / 196;
    int rem = b - n * 196;
    int ct  = rem / 49;
    int pt  = rem - ct * 49;
    int c0 = ct * 64, p0 = pt * 64;
    int t = threadIdx.x;

    const float* xs = x + (size_t)n * C_IN * PIX;
    int pc = t & 63, cr = t >> 6;   // read: coalesced along pixels
#pragma unroll
    for (int it = 0; it < 16; ++it) {
        int c = c0 + it * 4 + cr;
        tile[it * 4 + cr][pc] = xs[(size_t)c * PIX + p0 + pc];
    }
    __syncthreads();
    int cl = t & 63, pr = t >> 6;   // write: coalesced along channels
#pragma unroll
    for (int it = 0; it < 16; ++it) {
        int p = p0 + it * 4 + pr;
        int h = p / HW, w = p - h * HW;
        float v = tile[cl][it * 4 + pr];
        xpad[(((size_t)n * HP + (h + 1)) * WPAD + (w + 1)) * C_IN + c0 + cl] = __float2bfloat16(v);
    }
}

// ---------------- pass 2: binarize + transpose weights -> wt[cout][tap][c] bf16 -------
__global__ void wxform_kernel(const float* __restrict__ w, __hip_bfloat16* __restrict__ wt) {
    int i = blockIdx.x * 256 + threadIdx.x;   // over 589824
    if (i >= C_OUT * K_TOT) return;
    int cout = i / K_TOT;
    int r    = i - cout * K_TOT;
    int tap  = r >> 8;
    int c    = r & 255;
    float v = w[cout * 2304 + c * 9 + tap];   // [cout][cin][3][3]
    float s = (v > 0.f) ? 1.f : ((v < 0.f) ? -1.f : 0.f);
    wt[i] = __float2bfloat16(s);
}

// ---------------- pass 3: phase-split slab-reuse implicit-GEMM MFMA conv -------------
// v3: T2+T3+T4+T5 combo.
//  - LDS slab stored XOR-swizzled, staged by global_load_lds (linear dest, 16B,
//    pre-swizzled global source; read applies the same involution). Bank pattern
//    for a-frag ds_read_b128 = 2-way (free); staging write is linear (free).
//  - 9 phases per 32-chan chunk: {ds_read a(t) | 1 staging inst | b-load(t+1)}
//    -> s_barrier -> setprio(1) -> 28 MFMA -> setprio(0) -> s_barrier.
//  - vmcnt never drained inside a chunk (vmcnt(5) hint keeps 1 stage + 4 b in
//    flight); one __syncthreads() per chunk (emits vmcnt(0)) guards the LDS
//    double-buffer swap -- the ONLY correctness-bearing barrier.
__global__ void __launch_bounds__(256, 2)
gemm_kernel(const __hip_bfloat16* __restrict__ xpad,
            const __hip_bfloat16* __restrict__ wt,
            const float* __restrict__ bias,
            float* __restrict__ out) {
    __shared__ __hip_bfloat16 slab[2][SLAB_PIX * 32];   // 2 x 22272 B

    // XCD-pair swizzle: blocks bx and bx+8 share an XCD (bx%8); give them the
    // same M-tile (both N-tiles) so the A window is fetched once per XCD L2.
    int bx = blockIdx.x;                 // 896 blocks = 56 supergroups of 16
    int g = bx >> 4, xg = bx & 7, nt = (bx >> 3) & 1;
    int mt = g * 8 + xg;                 // 0..447
    int nimg = mt / 14, ti = mt - nimg * 14;
    int r0 = ti * 4;                     // first output row of this tile
    int n0 = nt * BN;

    int tid = threadIdx.x, lane = tid & 63, wid = tid >> 6;
    int wm = wid >> 1, wn = wid & 1;
    int ar = lane & 15;
    int kq = lane >> 4;                  // 0..3 (chan-group within 32-chan chunk)

    // per-frag pixel index in the slab for tap (0,0): m = wm*112 + i*16 + ar
    int p0[7];
#pragma unroll
    for (int i = 0; i < 7; ++i) {
        int m = wm * 112 + i * 16 + ar;
        int dr = m / 56, wcol = m - dr * 56;
        p0[i] = dr * 58 + wcol;
    }
    // per-lane B bases (elems into wt)
    long wb[4];
#pragma unroll
    for (int j = 0; j < 4; ++j) {
        int n = n0 + wn * 64 + j * 16 + ar;
        wb[j] = (long)n * K_TOT + kq * 8;
    }

    // the 6-row padded window is contiguous in xpad memory
    const __hip_bfloat16* srcBase = xpad + ((long)(nimg * HP + r0) * WPAD) * C_IN;

    f32x4_t acc[7][4] = {};

    // ---- prologue: stage chunk 0 into buf 0 (global_load_lds, swizzled source) ----
#pragma unroll
    for (int it = 0; it < 6; ++it) {
        int s = it * 256 + tid;
        if (s < SLAB_SLOTS) {
            int p = s >> 2, q = s & 3;
            const __hip_bfloat16* gsrc = srcBase + (long)p * C_IN + ((q ^ ((p >> 1) & 3)) * 8);
            __hip_bfloat16* ldst = &slab[0][(it * 256 + wid * 64) * 8];
            __builtin_amdgcn_global_load_lds(
                (const __attribute__((address_space(1))) void*)gsrc,
                (__attribute__((address_space(3))) void*)ldst, 16, 0, 0);
        }
    }
    // b for (tap 0, chunk 0)
    bf16x8_t bcur[4];
#pragma unroll
    for (int j = 0; j < 4; ++j) bcur[j] = *(const bf16x8_t*)&wt[wb[j]];
    __syncthreads();   // drains vmcnt(0): staging complete

    int cur = 0;
    for (int ch = 0; ch < 8; ++ch) {
        const __hip_bfloat16* sb = &slab[cur][0];
        __hip_bfloat16* nb = &slab[cur ^ 1][0];
#pragma unroll
        for (int t = 0; t < 9; ++t) {
            const int kh = t / 3, kw = t - kh * 3;
            const int dpx = kh * 58 + kw;

            // a-frag reads for tap t (swizzled: elem = p*32 + (kq^((p>>1)&3))*8)
            bf16x8_t a[7];
#pragma unroll
            for (int i = 0; i < 7; ++i) {
                int p = p0[i] + dpx;
                int off = (p << 5) + ((kq ^ ((p >> 1) & 3)) << 3);
                a[i] = *(const bf16x8_t*)(sb + off);
            }

            // one staging wave-inst per phase (t<6): next chunk -> other buffer
            if (ch < 7 && t < 6) {
                int s = t * 256 + tid;
                if (s < SLAB_SLOTS) {
                    int p = s >> 2, q = s & 3;
                    const __hip_bfloat16* gsrc =
                        srcBase + (long)p * C_IN + (ch + 1) * 32 + ((q ^ ((p >> 1) & 3)) * 8);
                    __hip_bfloat16* ldst = nb + (t * 256 + wid * 64) * 8;
                    __builtin_amdgcn_global_load_lds(
                        (const __attribute__((address_space(1))) void*)gsrc,
                        (__attribute__((address_space(3))) void*)ldst, 16, 0, 0);
                }
            }

            // b prefetch for the next phase (tap t+1, or tap 0 of next chunk)
            bf16x8_t bn[4];
            const bool last = (ch == 7) && (t == 8);
            if (!last) {
                const int tn = (t < 8) ? t + 1 : 0;
                const int cn = (t < 8) ? ch : ch + 1;
#pragma unroll
                for (int j = 0; j < 4; ++j)
                    bn[j] = *(const bf16x8_t*)&wt[wb[j] + tn * 256 + cn * 32];
            }

            // keep newest {1 stage + 4 b} in flight; older loads (this tap's b,
            // previous staging) must have landed. Scheduling hint only.
            asm volatile("s_waitcnt vmcnt(5)");
            __builtin_amdgcn_s_barrier();

            __builtin_amdgcn_s_setprio(1);
#pragma unroll
            for (int i = 0; i < 7; ++i)
#pragma unroll
                for (int j = 0; j < 4; ++j)
                    acc[i][j] = __builtin_amdgcn_mfma_f32_16x16x32_bf16(a[i], bcur[j], acc[i][j], 0, 0, 0);
            __builtin_amdgcn_s_setprio(0);

            if (t == 8) {
                if (ch < 7) __syncthreads();   // vmcnt(0)+lgkmcnt(0)+barrier: buffer swap guard
            } else {
                __builtin_amdgcn_s_barrier();  // scheduling barrier (no hazard crosses it)
            }
            if (!last) {
#pragma unroll
                for (int j = 0; j < 4; ++j) bcur[j] = bn[j];
            }
        }
        cur ^= 1;
    }

    // epilogue: C/D col=lane&15 (n), row=(lane>>4)*4+reg (m); m-consecutive regs
    // -> float4 stores (16B-aligned: rq multiple of 4)
    int cn = lane & 15;
    int rq = (lane >> 4) * 4;
    long outb = (long)nimg * OUT_IMG_STRIDE + r0 * 56;
#pragma unroll
    for (int i = 0; i < 7; ++i) {
        int mb = wm * 112 + i * 16 + rq;
#pragma unroll
        for (int j = 0; j < 4; ++j) {
            int cout = n0 + wn * 64 + j * 16 + cn;
            float bv = bias[cout];
            f32x4_t v = acc[i][j];
            v[0] += bv; v[1] += bv; v[2] += bv; v[3] += bv;
            *(f32x4_t*)&out[outb + (long)cout * PIX + mb] = v;
        }
    }
}

extern "C" void kernel_launch(void* const* d_in, const int* in_sizes, int n_in,
                              void* d_out, int out_size, void* d_ws, size_t ws_size,
                              hipStream_t stream) {
    const float* x    = (const float*)d_in[0];
    const float* wgt  = (const float*)d_in[1];
    const float* bias = (const float*)d_in[2];
    float* out = (float*)d_out;

    __hip_bfloat16* xpad = (__hip_bfloat16*)d_ws;                       // 55,115,776 B
    __hip_bfloat16* wt   = (__hip_bfloat16*)((char*)d_ws + 55115776);   // 1,179,648 B

    // pass 0: zero only the padded border (ws is re-poisoned before every call)
    border_zero_kernel<<<dim3((32 * 228 * 32 + 255) / 256), dim3(256), 0, stream>>>(xpad);

    // pass 1: NCHW fp32 -> padded NHWC bf16
    xform_kernel<<<dim3(N_IMG * 4 * 49), dim3(256), 0, stream>>>(x, xpad);

    // pass 2: binarize weights -> wt[cout][tap][c]
    wxform_kernel<<<dim3((C_OUT * K_TOT + 255) / 256), dim3(256), 0, stream>>>(wgt, wt);

    // pass 3: phase-split slab-reuse implicit GEMM (448 M-tiles x 2 N-tiles)
    gemm_kernel<<<dim3((M_TOT / BM) * (C_OUT / BN)), dim3(256), 0, stream>>>(xpad, wt, bias, out);
}

// Round 3
// 693.151 us; speedup vs baseline: 1.0660x; 1.0660x over previous
//
#include <hip/hip_runtime.h>
#include <hip/hip_bf16.h>
#include <stdint.h>

// ---- problem constants ----
#define N_IMG 32
#define C_IN  256
#define HW    56
#define PIX   3136            // 56*56
#define M_TOT 100352          // 32*3136
#define C_OUT 256
#define K_TOT 2304            // 256*9
#define HP    58
#define WPAD  58
#define OUT_IMG_STRIDE 802816 // 256*3136

// ---- GEMM tile config: BM=224 (4 image rows), BN=128, slab-reuse over 9 taps ----
#define BM 224
#define BN 128
#define SLAB_PIX 348                 // 6 padded rows * 58 cols
#define SLAB_SLOTS (SLAB_PIX * 4)    // 1392 16B slots per buffer (32 chans/pixel)

typedef __attribute__((ext_vector_type(8))) short bf16x8_t;   // 8 bf16 = 4 VGPRs
typedef __attribute__((ext_vector_type(4))) float f32x4_t;

// ---------------- pass 0: zero only the padded border (3.7 MB, not 55 MB) -----------
__global__ void border_zero_kernel(__hip_bfloat16* __restrict__ xpad) {
    int t = blockIdx.x * 256 + threadIdx.x;   // 32 n * 228 border px * 32 uint4 = 233472
    if (t >= 32 * 228 * 32) return;
    int n = t / (228 * 32);
    int r = t - n * (228 * 32);
    int px = r >> 5, part = r & 31;
    int hp, wp;
    if (px < 58)       { hp = 0;  wp = px; }
    else if (px < 116) { hp = 57; wp = px - 116 + 58; }
    else { int k = px - 116; hp = 1 + (k >> 1); wp = (k & 1) ? 57 : 0; }
    long e = (((long)n * HP + hp) * WPAD + wp) * C_IN + part * 8;
    *(uint4*)(xpad + e) = make_uint4(0u, 0u, 0u, 0u);
}

// ---------------- pass 1: NCHW fp32 -> padded NHWC bf16 transpose --------------------
__global__ void xform_kernel(const float* __restrict__ x, __hip_bfloat16* __restrict__ xpad) {
    __shared__ float tile[64][65];
    int b   = blockIdx.x;
    int n   = b / 196;
    int rem = b - n * 196;
    int ct  = rem / 49;
    int pt  = rem - ct * 49;
    int c0 = ct * 64, p0 = pt * 64;
    int t = threadIdx.x;

    const float* xs = x + (size_t)n * C_IN * PIX;
    int pc = t & 63, cr = t >> 6;   // read: coalesced along pixels
#pragma unroll
    for (int it = 0; it < 16; ++it) {
        int c = c0 + it * 4 + cr;
        tile[it * 4 + cr][pc] = xs[(size_t)c * PIX + p0 + pc];
    }
    __syncthreads();
    int cl = t & 63, pr = t >> 6;   // write: coalesced along channels
#pragma unroll
    for (int it = 0; it < 16; ++it) {
        int p = p0 + it * 4 + pr;
        int h = p / HW, w = p - h * HW;
        float v = tile[cl][it * 4 + pr];
        xpad[(((size_t)n * HP + (h + 1)) * WPAD + (w + 1)) * C_IN + c0 + cl] = __float2bfloat16(v);
    }
}

// ---------------- pass 2: binarize + transpose weights -> wt[cout][tap][c] bf16 -------
__global__ void wxform_kernel(const float* __restrict__ w, __hip_bfloat16* __restrict__ wt) {
    int i = blockIdx.x * 256 + threadIdx.x;   // over 589824
    if (i >= C_OUT * K_TOT) return;
    int cout = i / K_TOT;
    int r    = i - cout * K_TOT;
    int tap  = r >> 8;
    int c    = r & 255;
    float v = w[cout * 2304 + c * 9 + tap];   // [cout][cin][3][3]
    float s = (v > 0.f) ? 1.f : ((v < 0.f) ? -1.f : 0.f);
    wt[i] = __float2bfloat16(s);
}

// ---------------- pass 3: 2-phase gload_lds slab-reuse implicit-GEMM MFMA conv -------
// v4: minimum-2-phase template (catalog T3 recipe) + v3's proven XOR swizzle.
//  - Staging: global_load_lds 16B, linear LDS dest, pre-swizzled global source
//    (slot q holds chan-part q^((p>>1)&3)); read applies the same XOR ->
//    a-frag ds_read_b128 bank pattern is 2-way (free), staging write is linear.
//    (v3 measured: bank conflicts 9.5M -> 1.0M with this layout.)
//  - Per chunk: issue next chunk's 6 gload_lds into buf^1 FIRST, then the
//    9-tap x 28-MFMA compute on buf, then ONE __syncthreads() (its vmcnt(0)
//    drain is the buffer-swap guard; ~2500 cy of MFMA covers staging latency).
//  - No persistent prefetch registers, no raw barriers, no asm waitcnt:
//    v3's spill disaster came from hand-pinning live ranges past the 128-VGPR
//    budget. Arch regs here: ~90 + 112 acc AGPR -> no spill at 2 waves/SIMD.
__global__ void __launch_bounds__(256, 2)
gemm_kernel(const __hip_bfloat16* __restrict__ xpad,
            const __hip_bfloat16* __restrict__ wt,
            const float* __restrict__ bias,
            float* __restrict__ out) {
    __shared__ __hip_bfloat16 slab[2][SLAB_PIX * 32];   // 2 x 22272 B

    // XCD-pair swizzle: blocks bx and bx+8 share an XCD (bx%8); give them the
    // same M-tile (both N-tiles) so the A window is fetched once per XCD L2.
    int bx = blockIdx.x;                 // 896 blocks = 56 supergroups of 16
    int g = bx >> 4, xg = bx & 7, nt = (bx >> 3) & 1;
    int mt = g * 8 + xg;                 // 0..447
    int nimg = mt / 14, ti = mt - nimg * 14;
    int r0 = ti * 4;                     // first output row of this tile
    int n0 = nt * BN;

    int tid = threadIdx.x, lane = tid & 63, wid = tid >> 6;
    int wm = wid >> 1, wn = wid & 1;
    int ar = lane & 15;
    int kq = lane >> 4;                  // 0..3 (chan-group within 32-chan chunk)

    // per-frag pixel index in the slab for tap (0,0): m = wm*112 + i*16 + ar
    int p0[7];
#pragma unroll
    for (int i = 0; i < 7; ++i) {
        int m = wm * 112 + i * 16 + ar;
        int dr = m / 56, wcol = m - dr * 56;
        p0[i] = dr * 58 + wcol;
    }
    // per-lane B bases (elems into wt)
    long wb[4];
#pragma unroll
    for (int j = 0; j < 4; ++j) {
        int n = n0 + wn * 64 + j * 16 + ar;
        wb[j] = (long)n * K_TOT + kq * 8;
    }

    // the 6-row padded window is contiguous in xpad memory
    const __hip_bfloat16* srcBase = xpad + ((long)(nimg * HP + r0) * WPAD) * C_IN;

    // stage chunk `chnk` into `buf` via global_load_lds (wave-uniform dest base,
    // per-lane pre-swizzled global source)
    auto stage = [&](int chnk, __hip_bfloat16* buf) {
#pragma unroll
        for (int it = 0; it < 6; ++it) {
            int s = it * 256 + tid;
            if (s < SLAB_SLOTS) {
                int p = s >> 2, q = s & 3;
                const __hip_bfloat16* gsrc =
                    srcBase + (long)p * C_IN + chnk * 32 + ((q ^ ((p >> 1) & 3)) * 8);
                __hip_bfloat16* ldst = buf + (it * 256 + wid * 64) * 8;
                __builtin_amdgcn_global_load_lds(
                    (const __attribute__((address_space(1))) void*)gsrc,
                    (__attribute__((address_space(3))) void*)ldst, 16, 0, 0);
            }
        }
    };

    f32x4_t acc[7][4] = {};

    // ---- prologue: stage chunk 0 into buf 0 ----
    stage(0, &slab[0][0]);
    __syncthreads();   // vmcnt(0) drain: chunk 0 resident

    int cur = 0;
    for (int ch = 0; ch < 8; ++ch) {
        // issue next chunk's staging FIRST (lands during the MFMA phase)
        if (ch < 7) stage(ch + 1, &slab[cur ^ 1][0]);

        const __hip_bfloat16* sb = &slab[cur][0];
        __builtin_amdgcn_s_setprio(1);
#pragma unroll
        for (int t = 0; t < 9; ++t) {
            const int kh = t / 3, kw = t - kh * 3;
            const int dpx = kh * 58 + kw;
            bf16x8_t b[4];
#pragma unroll
            for (int j = 0; j < 4; ++j)
                b[j] = *(const bf16x8_t*)&wt[wb[j] + t * 256 + ch * 32];
            bf16x8_t a[7];
#pragma unroll
            for (int i = 0; i < 7; ++i) {
                int p = p0[i] + dpx;
                int off = (p << 5) + ((kq ^ ((p >> 1) & 3)) << 3);
                a[i] = *(const bf16x8_t*)(sb + off);
            }
#pragma unroll
            for (int i = 0; i < 7; ++i)
#pragma unroll
                for (int j = 0; j < 4; ++j)
                    acc[i][j] = __builtin_amdgcn_mfma_f32_16x16x32_bf16(a[i], b[j], acc[i][j], 0, 0, 0);
        }
        __builtin_amdgcn_s_setprio(0);

        // ONE barrier per chunk: drains vmcnt(0) (staging done) + lgkmcnt,
        // guards the double-buffer swap. No other sync needed.
        if (ch < 7) __syncthreads();
        cur ^= 1;
    }

    // epilogue: C/D col=lane&15 (n), row=(lane>>4)*4+reg (m); m-consecutive regs
    // -> float4 stores (16B-aligned: rq multiple of 4)
    int cn = lane & 15;
    int rq = (lane >> 4) * 4;
    long outb = (long)nimg * OUT_IMG_STRIDE + r0 * 56;
#pragma unroll
    for (int i = 0; i < 7; ++i) {
        int mb = wm * 112 + i * 16 + rq;
#pragma unroll
        for (int j = 0; j < 4; ++j) {
            int cout = n0 + wn * 64 + j * 16 + cn;
            float bv = bias[cout];
            f32x4_t v = acc[i][j];
            v[0] += bv; v[1] += bv; v[2] += bv; v[3] += bv;
            *(f32x4_t*)&out[outb + (long)cout * PIX + mb] = v;
        }
    }
}

extern "C" void kernel_launch(void* const* d_in, const int* in_sizes, int n_in,
                              void* d_out, int out_size, void* d_ws, size_t ws_size,
                              hipStream_t stream) {
    const float* x    = (const float*)d_in[0];
    const float* wgt  = (const float*)d_in[1];
    const float* bias = (const float*)d_in[2];
    float* out = (float*)d_out;

    __hip_bfloat16* xpad = (__hip_bfloat16*)d_ws;                       // 55,115,776 B
    __hip_bfloat16* wt   = (__hip_bfloat16*)((char*)d_ws + 55115776);   // 1,179,648 B

    // pass 0: zero only the padded border (ws is re-poisoned before every call)
    border_zero_kernel<<<dim3((32 * 228 * 32 + 255) / 256), dim3(256), 0, stream>>>(xpad);

    // pass 1: NCHW fp32 -> padded NHWC bf16
    xform_kernel<<<dim3(N_IMG * 4 * 49), dim3(256), 0, stream>>>(x, xpad);

    // pass 2: binarize weights -> wt[cout][tap][c]
    wxform_kernel<<<dim3((C_OUT * K_TOT + 255) / 256), dim3(256), 0, stream>>>(wgt, wt);

    // pass 3: 2-phase double-buffered slab-reuse implicit GEMM
    gemm_kernel<<<dim3((M_TOT / BM) * (C_OUT / BN)), dim3(256), 0, stream>>>(xpad, wt, bias, out);
}

// Round 4
// 349.197 us; speedup vs baseline: 2.1159x; 1.9850x over previous
//
#include <hip/hip_runtime.h>
#include <hip/hip_bf16.h>
#include <stdint.h>

// ---- problem constants ----
#define N_IMG 32
#define C_IN  256
#define HW    56
#define PIX   3136            // 56*56
#define M_TOT 100352          // 32*3136
#define C_OUT 256
#define K_TOT 2304            // 256*9
#define HP    58
#define WPAD  58
#define OUT_IMG_STRIDE 802816 // 256*3136

// ---- GEMM tile config: BM=224 (4 image rows), BN=128, slab-reuse over 9 taps ----
#define BM 224
#define BN 128
#define SLAB_PIX 348                 // 6 padded rows * 58 cols
#define SLAB_SLOTS (SLAB_PIX * 4)    // 1392 16B slots (32 chans/pixel, 4 parts of 8)

typedef __attribute__((ext_vector_type(8))) short bf16x8_t;   // 8 bf16 = 4 VGPRs
typedef __attribute__((ext_vector_type(4))) float f32x4_t;

// ---------------- pass 0: zero only the padded border (3.7 MB, not 55 MB) -----------
__global__ void border_zero_kernel(__hip_bfloat16* __restrict__ xpad) {
    int t = blockIdx.x * 256 + threadIdx.x;   // 32 n * 228 border px * 32 uint4 = 233472
    if (t >= 32 * 228 * 32) return;
    int n = t / (228 * 32);
    int r = t - n * (228 * 32);
    int px = r >> 5, part = r & 31;
    int hp, wp;
    if (px < 58)       { hp = 0;  wp = px; }
    else if (px < 116) { hp = 57; wp = px - 116 + 58; }
    else { int k = px - 116; hp = 1 + (k >> 1); wp = (k & 1) ? 57 : 0; }
    long e = (((long)n * HP + hp) * WPAD + wp) * C_IN + part * 8;
    *(uint4*)(xpad + e) = make_uint4(0u, 0u, 0u, 0u);
}

// ---------------- pass 1: NCHW fp32 -> padded NHWC bf16 transpose --------------------
__global__ void xform_kernel(const float* __restrict__ x, __hip_bfloat16* __restrict__ xpad) {
    __shared__ float tile[64][65];
    int b   = blockIdx.x;
    int n   = b / 196;
    int rem = b - n * 196;
    int ct  = rem / 49;
    int pt  = rem - ct * 49;
    int c0 = ct * 64, p0 = pt * 64;
    int t = threadIdx.x;

    const float* xs = x + (size_t)n * C_IN * PIX;
    int pc = t & 63, cr = t >> 6;   // read: coalesced along pixels
#pragma unroll
    for (int it = 0; it < 16; ++it) {
        int c = c0 + it * 4 + cr;
        tile[it * 4 + cr][pc] = xs[(size_t)c * PIX + p0 + pc];
    }
    __syncthreads();
    int cl = t & 63, pr = t >> 6;   // write: coalesced along channels
#pragma unroll
    for (int it = 0; it < 16; ++it) {
        int p = p0 + it * 4 + pr;
        int h = p / HW, w = p - h * HW;
        float v = tile[cl][it * 4 + pr];
        xpad[(((size_t)n * HP + (h + 1)) * WPAD + (w + 1)) * C_IN + c0 + cl] = __float2bfloat16(v);
    }
}

// ---------------- pass 2: binarize + transpose weights -> wt[cout][tap][c] bf16 -------
__global__ void wxform_kernel(const float* __restrict__ w, __hip_bfloat16* __restrict__ wt) {
    int i = blockIdx.x * 256 + threadIdx.x;   // over 589824
    if (i >= C_OUT * K_TOT) return;
    int cout = i / K_TOT;
    int r    = i - cout * K_TOT;
    int tap  = r >> 8;
    int c    = r & 255;
    float v = w[cout * 2304 + c * 9 + tap];   // [cout][cin][3][3]
    float s = (v > 0.f) ? 1.f : ((v < 0.f) ? -1.f : 0.f);
    wt[i] = __float2bfloat16(s);
}

// ---------------- pass 3: slab-reuse implicit-GEMM MFMA conv -------------------------
// v5 = round-0 structure (best verified: 178.7 us) + ONE change: the LDS slab
// layout. 80B-stride pad -> linear 64B/pixel + XOR swizzle: slot (p,q) holds
// global chan-part q^((p>>1)&3). ds_write dest is linear (64 lanes -> 1024B
// contiguous, conflict-free); a-frag ds_read_b128 applies the same XOR.
// v3/v4 hardware-verified this layout correct and measured bank conflicts
// 9.5M -> 1.03M. Staging stays reg-based (uint4 + ds_write): the gload_lds
// variants (v3/v4) showed 4-8x HBM traffic blowups — reverted.
__global__ void __launch_bounds__(256, 2)
gemm_kernel(const __hip_bfloat16* __restrict__ xpad,
            const __hip_bfloat16* __restrict__ wt,
            const float* __restrict__ bias,
            float* __restrict__ out) {
    __shared__ __hip_bfloat16 slab[SLAB_PIX * 32];   // 22272 B

    // XCD-pair swizzle: blocks bx and bx+8 share an XCD (bx%8); give them the
    // same M-tile (both N-tiles) so the A window is fetched once per XCD L2.
    int bx = blockIdx.x;                 // 896 blocks = 56 supergroups of 16
    int g = bx >> 4, xg = bx & 7, nt = (bx >> 3) & 1;
    int mt = g * 8 + xg;                 // 0..447
    int nimg = mt / 14, ti = mt - nimg * 14;
    int r0 = ti * 4;                     // first output row of this tile
    int n0 = nt * BN;

    int tid = threadIdx.x, lane = tid & 63, wid = tid >> 6;
    int wm = wid >> 1, wn = wid & 1;
    int ar = lane & 15;
    int kq = lane >> 4;                  // 0..3 (chan-part within 32-chan chunk)

    // per-frag pixel index in the slab for tap (0,0): m = wm*112 + i*16 + ar
    int p0[7];
#pragma unroll
    for (int i = 0; i < 7; ++i) {
        int m = wm * 112 + i * 16 + ar;
        int dr = m / 56, wcol = m - dr * 56;
        p0[i] = dr * 58 + wcol;
    }
    // per-lane B bases (elems into wt)
    long wb[4];
#pragma unroll
    for (int j = 0; j < 4; ++j) {
        int n = n0 + wn * 64 + j * 16 + ar;
        wb[j] = (long)n * K_TOT + kq * 8;
    }

    // the 6-row padded window is contiguous in xpad memory
    const __hip_bfloat16* srcBase = xpad + ((long)(nimg * HP + r0) * WPAD) * C_IN;

    f32x4_t acc[7][4] = {};

    for (int ch = 0; ch < 8; ++ch) {
        if (ch) __syncthreads();
        // stage slab: 1392 16B slots, linear LDS dest, XOR-swizzled source part.
        // slot s=(p,q) at byte s*16 holds chan-part (q ^ ((p>>1)&3)) of pixel p.
#pragma unroll
        for (int it = 0; it < 6; ++it) {
            int s = it * 256 + tid;
            if (s < SLAB_SLOTS) {
                int p = s >> 2, q = s & 3;
                uint4 v = *(const uint4*)(srcBase + (long)p * C_IN + ch * 32
                                          + ((q ^ ((p >> 1) & 3)) * 8));
                *(uint4*)((char*)slab + s * 16) = v;
            }
        }
        __syncthreads();

#pragma unroll
        for (int t = 0; t < 9; ++t) {
            const int kh = t / 3, kw = t - kh * 3;
            const int dpx = kh * 58 + kw;
            bf16x8_t b[4];
#pragma unroll
            for (int j = 0; j < 4; ++j)
                b[j] = *(const bf16x8_t*)&wt[wb[j] + t * 256 + ch * 32];
            bf16x8_t a[7];
#pragma unroll
            for (int i = 0; i < 7; ++i) {
                int p = p0[i] + dpx;
                int off = (p << 5) + ((kq ^ ((p >> 1) & 3)) << 3);   // elems
                a[i] = *(const bf16x8_t*)&slab[off];
            }
#pragma unroll
            for (int i = 0; i < 7; ++i)
#pragma unroll
                for (int j = 0; j < 4; ++j)
                    acc[i][j] = __builtin_amdgcn_mfma_f32_16x16x32_bf16(a[i], b[j], acc[i][j], 0, 0, 0);
        }
    }

    // epilogue: C/D col=lane&15 (n), row=(lane>>4)*4+reg (m); m-consecutive regs
    // -> float4 stores (16B-aligned: rq multiple of 4)
    int cn = lane & 15;
    int rq = (lane >> 4) * 4;
    long outb = (long)nimg * OUT_IMG_STRIDE + r0 * 56;
#pragma unroll
    for (int i = 0; i < 7; ++i) {
        int mb = wm * 112 + i * 16 + rq;
#pragma unroll
        for (int j = 0; j < 4; ++j) {
            int cout = n0 + wn * 64 + j * 16 + cn;
            float bv = bias[cout];
            f32x4_t v = acc[i][j];
            v[0] += bv; v[1] += bv; v[2] += bv; v[3] += bv;
            *(f32x4_t*)&out[outb + (long)cout * PIX + mb] = v;
        }
    }
}

extern "C" void kernel_launch(void* const* d_in, const int* in_sizes, int n_in,
                              void* d_out, int out_size, void* d_ws, size_t ws_size,
                              hipStream_t stream) {
    const float* x    = (const float*)d_in[0];
    const float* wgt  = (const float*)d_in[1];
    const float* bias = (const float*)d_in[2];
    float* out = (float*)d_out;

    __hip_bfloat16* xpad = (__hip_bfloat16*)d_ws;                       // 55,115,776 B
    __hip_bfloat16* wt   = (__hip_bfloat16*)((char*)d_ws + 55115776);   // 1,179,648 B

    // pass 0: zero only the padded border (ws is re-poisoned before every call)
    border_zero_kernel<<<dim3((32 * 228 * 32 + 255) / 256), dim3(256), 0, stream>>>(xpad);

    // pass 1: NCHW fp32 -> padded NHWC bf16
    xform_kernel<<<dim3(N_IMG * 4 * 49), dim3(256), 0, stream>>>(x, xpad);

    // pass 2: binarize weights -> wt[cout][tap][c]
    wxform_kernel<<<dim3((C_OUT * K_TOT + 255) / 256), dim3(256), 0, stream>>>(wgt, wt);

    // pass 3: slab-reuse implicit GEMM (448 M-tiles x 2 N-tiles, XCD-pair swizzled)
    gemm_kernel<<<dim3((M_TOT / BM) * (C_OUT / BN)), dim3(256), 0, stream>>>(xpad, wt, bias, out);
}